// Round 2
// baseline (503.119 us; speedup 1.0000x reference)
//
#include <hip/hip_runtime.h>
#include <cstdint>
#include <cstddef>

#define NNODE 512
#define MMASK 256
#define ZT 1e-9f

// ---------------- prep: ELL build (pad col=0, w=0) + x transpose ----------------
__global__ __launch_bounds__(256) void k_prep(const float* __restrict__ x,
                                              const float* __restrict__ S,
                                              int* __restrict__ sp_col, int* __restrict__ sp_cnt,
                                              int* __restrict__ s_col, float* __restrict__ s_val,
                                              int* __restrict__ s_cnt,
                                              float* __restrict__ xt) {
  int gtid = blockIdx.x * 256 + threadIdx.x;    // grid 128x256 = 32768
  int W = gtid >> 6, lane = threadIdx.x & 63;
  // transpose x: (B,N) -> (N,B)
  {
    int n = gtid >> 6, b = gtid & 63;
    xt[gtid] = x[b * NNODE + n];
  }
  // ELL fill, one wave per row
  int m = W;
  int csp = 0, cs = 0;
  unsigned long long lt = (1ull << lane) - 1ull;
  for (int ch = 0; ch < 8; ++ch) {
    int n = ch * 64 + lane;
    float s = S[m * NNODE + n];
    bool ps  = (s != 0.f);
    bool psp = ((fabsf(s) + ((m == n) ? 1.f : 0.f)) > ZT) && !((m >= MMASK) && (n >= MMASK));
    unsigned long long msp = __ballot(psp), ms = __ballot(ps);
    if (psp) { int p = csp + __popcll(msp & lt); if (p < 64) sp_col[(m << 6) + p] = n; }
    if (ps)  { int p = cs  + __popcll(ms  & lt); if (p < 64) { s_col[(m << 6) + p] = n; s_val[(m << 6) + p] = s; } }
    csp += __popcll(msp); cs += __popcll(ms);
  }
  if (lane >= csp) sp_col[(m << 6) + lane] = 0;                       // pad col -> 0
  if (lane >= cs)  { s_col[(m << 6) + lane] = 0; s_val[(m << 6) + lane] = 0.f; }
  if (lane == 0) { sp_cnt[m] = (csp < 64 ? csp : 64); s_cnt[m] = (cs < 64 ? cs : 64); }
}

// ---------------- ELL row MAC, dense-gather weights ----------------
// cols / wrow are wave-uniform pointers (job index readfirstlane'd): cols[] and
// wrow[c] become batched/scattered scalar loads; only the z-gather is a vector
// load. Pads (col 0) are valid addresses; their weight is zeroed by a uniform
// scalar select, so no OOB and no wrong contribution.
__device__ __forceinline__ float ell_mac_gd(const int* __restrict__ cols,
                                            const float* __restrict__ wrow,   // dense 512-float row
                                            int cnt,
                                            const float* __restrict__ zin, int lane) {
  float a0 = 0.f, a1 = 0.f, a2 = 0.f, a3 = 0.f;
  for (int base = 0; base < cnt; base += 8) {
#pragma unroll
    for (int i = 0; i < 8; i += 4) {
      int j = base + i;
      int c0 = cols[j], c1 = cols[j + 1], c2 = cols[j + 2], c3 = cols[j + 3];
      float w0 = wrow[c0]; w0 = (j     < cnt) ? w0 : 0.f;
      float w1 = wrow[c1]; w1 = (j + 1 < cnt) ? w1 : 0.f;
      float w2 = wrow[c2]; w2 = (j + 2 < cnt) ? w2 : 0.f;
      float w3 = wrow[c3]; w3 = (j + 3 < cnt) ? w3 : 0.f;
      a0 += w0 * zin[(c0 << 6) + lane];
      a1 += w1 * zin[(c1 << 6) + lane];
      a2 += w2 * zin[(c2 << 6) + lane];
      a3 += w3 * zin[(c3 << 6) + lane];
    }
  }
  return (a0 + a1) + (a2 + a3);
}

// ---------------- ELL row MAC, packed weights (LSI path) ----------------
__device__ __forceinline__ float ell_mac_s(const int* __restrict__ cols,
                                           const float* __restrict__ ws,
                                           int cnt,
                                           const float* __restrict__ zin, int lane) {
  float a0 = 0.f, a1 = 0.f, a2 = 0.f, a3 = 0.f;
  for (int base = 0; base < cnt; base += 16) {
#pragma unroll
    for (int i = 0; i < 16; i += 4) {
      int   c0 = cols[base + i    ]; float w0 = ws[base + i    ];
      int   c1 = cols[base + i + 1]; float w1 = ws[base + i + 1];
      int   c2 = cols[base + i + 2]; float w2 = ws[base + i + 2];
      int   c3 = cols[base + i + 3]; float w3 = ws[base + i + 3];
      a0 += w0 * zin[(c0 << 6) + lane];
      a1 += w1 * zin[(c1 << 6) + lane];
      a2 += w2 * zin[(c2 << 6) + lane];
      a3 += w3 * zin[(c3 << 6) + lane];
    }
  }
  return (a0 + a1) + (a2 + a3);
}

// ---------------- layer 1 steps ----------------
__global__ __launch_bounds__(256) void k_l1s0(const float* __restrict__ wEV1,
    const int* __restrict__ sp_col, const int* __restrict__ sp_cnt,
    const int* __restrict__ s_col, const float* __restrict__ s_val, const int* __restrict__ s_cnt,
    const float* __restrict__ xt, float* __restrict__ zA1, float* __restrict__ u1) {
  int lane = threadIdx.x & 63;
  int W = __builtin_amdgcn_readfirstlane((blockIdx.x * 256 + (int)threadIdx.x) >> 6);
  int nwv = (gridDim.x << 2);
  for (int u = W; u < 4608; u += nwv) {
    if (u < 4096) {
      int f = u >> 9, r = u & 511;
      zA1[((size_t)f << 15) + (r << 6) + lane] =
          ell_mac_gd(sp_col + (r << 6), wEV1 + ((size_t)(f * 3 + 0) << 18) + (r << 9),
                     sp_cnt[r], xt, lane);
    } else {
      int r = u - 4096;
      u1[(r << 6) + lane] =
          ell_mac_s(s_col + (r << 6), s_val + (r << 6), s_cnt[r], xt, lane);
    }
  }
}

__global__ __launch_bounds__(256) void k_l1s1(const float* __restrict__ wEV1,
    const int* __restrict__ sp_col, const int* __restrict__ sp_cnt,
    const int* __restrict__ s_col, const float* __restrict__ s_val, const int* __restrict__ s_cnt,
    const float* __restrict__ zA1, const float* __restrict__ u1,
    float* __restrict__ zB1, float* __restrict__ u2) {
  int lane = threadIdx.x & 63;
  int W = __builtin_amdgcn_readfirstlane((blockIdx.x * 256 + (int)threadIdx.x) >> 6);
  int nwv = (gridDim.x << 2);
  for (int u = W; u < 4608; u += nwv) {
    if (u < 4096) {
      int f = u >> 9, r = u & 511;
      zB1[((size_t)f << 15) + (r << 6) + lane] =
          ell_mac_gd(sp_col + (r << 6), wEV1 + ((size_t)(f * 3 + 1) << 18) + (r << 9),
                     sp_cnt[r], zA1 + ((size_t)f << 15), lane);
    } else {
      int r = u - 4096;
      u2[(r << 6) + lane] =
          ell_mac_s(s_col + (r << 6), s_val + (r << 6), s_cnt[r], u1, lane);
    }
  }
}

__global__ __launch_bounds__(256) void k_l1s2(const float* __restrict__ wEV1,
    const int* __restrict__ sp_col, const int* __restrict__ sp_cnt,
    const float* __restrict__ zA1, const float* __restrict__ zB1,
    const float* __restrict__ xt, const float* __restrict__ u1, const float* __restrict__ u2,
    const float* __restrict__ wLSI1, const float* __restrict__ b1, float* __restrict__ y1) {
  int lane = threadIdx.x & 63;
  int W = __builtin_amdgcn_readfirstlane((blockIdx.x * 256 + (int)threadIdx.x) >> 6);
  int nwv = (gridDim.x << 2);
  for (int u = W; u < 4096; u += nwv) {
    int f = u >> 9, r = u & 511;
    float a = ell_mac_gd(sp_col + (r << 6), wEV1 + ((size_t)(f * 3 + 2) << 18) + (r << 9),
                         sp_cnt[r], zB1 + ((size_t)f << 15), lane);
    int idx = (r << 6) + lane;
    size_t fi = ((size_t)f << 15) + idx;
    y1[fi] = zA1[fi] + zB1[fi] + a
           + wLSI1[f * 3 + 0] * xt[idx] + wLSI1[f * 3 + 1] * u1[idx]
           + wLSI1[f * 3 + 2] * u2[idx] + b1[f];
  }
}

// ---------------- layer 2 steps ----------------
__global__ __launch_bounds__(256) void k_l2s0(const float* __restrict__ wEV2,
    const int* __restrict__ sp_col, const int* __restrict__ sp_cnt,
    const int* __restrict__ s_col, const float* __restrict__ s_val, const int* __restrict__ s_cnt,
    const float* __restrict__ y1, float* __restrict__ zA2, float* __restrict__ v1) {
  int lane = threadIdx.x & 63;
  int W = __builtin_amdgcn_readfirstlane((blockIdx.x * 256 + (int)threadIdx.x) >> 6);
  int nwv = (gridDim.x << 2);
  for (int u = W; u < 36864; u += nwv) {
    if (u < 32768) {
      int c = u >> 9, r = u & 511;
      int f = c >> 3, g = c & 7;
      zA2[((size_t)c << 15) + (r << 6) + lane] =
          ell_mac_gd(sp_col + (r << 6),
                     wEV2 + ((size_t)((f * 3 + 0) * 8 + g) << 18) + (r << 9),
                     sp_cnt[r], y1 + ((size_t)g << 15), lane);
    } else {
      int t = u - 32768;
      int g = t >> 9, r = t & 511;
      v1[((size_t)g << 15) + (r << 6) + lane] =
          ell_mac_s(s_col + (r << 6), s_val + (r << 6), s_cnt[r],
                    y1 + ((size_t)g << 15), lane);
    }
  }
}

__global__ __launch_bounds__(256) void k_l2s1(const float* __restrict__ wEV2,
    const int* __restrict__ sp_col, const int* __restrict__ sp_cnt,
    const int* __restrict__ s_col, const float* __restrict__ s_val, const int* __restrict__ s_cnt,
    const float* __restrict__ zA2, const float* __restrict__ v1,
    float* __restrict__ zB2, float* __restrict__ v2) {
  int lane = threadIdx.x & 63;
  int W = __builtin_amdgcn_readfirstlane((blockIdx.x * 256 + (int)threadIdx.x) >> 6);
  int nwv = (gridDim.x << 2);
  for (int u = W; u < 36864; u += nwv) {
    if (u < 32768) {
      int c = u >> 9, r = u & 511;
      int f = c >> 3, g = c & 7;
      zB2[((size_t)c << 15) + (r << 6) + lane] =
          ell_mac_gd(sp_col + (r << 6),
                     wEV2 + ((size_t)((f * 3 + 1) * 8 + g) << 18) + (r << 9),
                     sp_cnt[r], zA2 + ((size_t)c << 15), lane);
    } else {
      int t = u - 32768;
      int g = t >> 9, r = t & 511;
      v2[((size_t)g << 15) + (r << 6) + lane] =
          ell_mac_s(s_col + (r << 6), s_val + (r << 6), s_cnt[r],
                    v1 + ((size_t)g << 15), lane);
    }
  }
}

// k2 step: one (f,r) job covers all 8 g -> direct y2 write, no atomics. ht init folded.
__global__ __launch_bounds__(256) void k_l2s2(const float* __restrict__ wEV2,
    const int* __restrict__ sp_col, const int* __restrict__ sp_cnt,
    const float* __restrict__ zA2, const float* __restrict__ zB2,
    const float* __restrict__ y1, const float* __restrict__ v1, const float* __restrict__ v2,
    const float* __restrict__ wLSI2, const float* __restrict__ b2,
    const float* __restrict__ bW1, float* __restrict__ y2, float* __restrict__ ht) {
  int gtid = blockIdx.x * 256 + threadIdx.x;
  int lane = threadIdx.x & 63;
  int W = __builtin_amdgcn_readfirstlane(gtid >> 6);
  int nwv = (gridDim.x << 2);
  if (gtid < 32768) ht[gtid] = bW1[gtid >> 6];
  for (int u = W; u < 4096; u += nwv) {
    int f = u >> 9, r = u & 511;
    int idx = (r << 6) + lane;
    const int* cols = sp_col + (r << 6);
    int cnt = sp_cnt[r];
    float acc = b2[f];
#pragma unroll
    for (int g = 0; g < 8; ++g) {
      int c = f * 8 + g;
      float a = ell_mac_gd(cols,
                           wEV2 + ((size_t)((f * 3 + 2) * 8 + g) << 18) + (r << 9),
                           cnt, zB2 + ((size_t)c << 15), lane);
      size_t ci = ((size_t)c << 15) + idx;
      size_t gi = ((size_t)g << 15) + idx;
      acc += zA2[ci] + zB2[ci] + a
           + wLSI2[f * 24 + g]      * y1[gi]
           + wLSI2[f * 24 + 8 + g]  * v1[gi]
           + wLSI2[f * 24 + 16 + g] * v2[gi];
    }
    y2[((size_t)f << 15) + idx] = acc;
  }
}

// ---------------- readout ----------------
__global__ __launch_bounds__(256) void k_gemm1(const float* __restrict__ W1,
                                               const float* __restrict__ y2,
                                               const float* __restrict__ bW2,
                                               float* __restrict__ ht,
                                               float* __restrict__ out) {
  int gtid = blockIdx.x * 256 + threadIdx.x;
  int lane = threadIdx.x & 63;
  int W = __builtin_amdgcn_readfirstlane(gtid >> 6);
  int nwv = (gridDim.x << 2);
  if (gtid < 8192) out[gtid] = bW2[gtid & 127];
  for (int u = W; u < 2048; u += nwv) {
    int pg = u >> 5, qs = u & 31;
    const float* wrow = W1 + (size_t)pg * 8 * 4096 + qs * 128;   // uniform -> s_load
    const float* yb = y2 + ((size_t)(qs * 128) << 6);
    float acc[8] = {0, 0, 0, 0, 0, 0, 0, 0};
    for (int q = 0; q < 128; q += 8) {
      float yv[8];
#pragma unroll
      for (int i = 0; i < 8; ++i) yv[i] = yb[((q + i) << 6) + lane];
#pragma unroll
      for (int i = 0; i < 8; ++i) {
#pragma unroll
        for (int p = 0; p < 8; ++p) acc[p] += wrow[(size_t)p * 4096 + q + i] * yv[i];
      }
    }
#pragma unroll
    for (int p = 0; p < 8; ++p) atomicAdd(&ht[((pg * 8 + p) << 6) + lane], acc[p]);
  }
}

__global__ __launch_bounds__(256) void k_gemm2(const float* __restrict__ W2,
                                               const float* __restrict__ ht,
                                               float* __restrict__ out) {
  int lane = threadIdx.x & 63;
  int W = __builtin_amdgcn_readfirstlane((blockIdx.x * 256 + (int)threadIdx.x) >> 6);
  int nwv = (gridDim.x << 2);
  for (int u = W; u < 1024; u += nwv) {
    int o = u >> 3, qs = u & 7;
    const float* w2 = W2 + (size_t)o * 512 + qs * 64;            // uniform -> s_load
    const float* hb = ht + ((size_t)(qs * 64) << 6);
    float acc = 0.f;
    for (int q = 0; q < 64; q += 8) {
#pragma unroll
      for (int i = 0; i < 8; ++i) acc += w2[q + i] * hb[((q + i) << 6) + lane];
    }
    atomicAdd(&out[lane * 128 + o], acc);
  }
}

extern "C" void kernel_launch(void* const* d_in, const int* in_sizes, int n_in,
                              void* d_out, int out_size, void* d_ws, size_t ws_size,
                              hipStream_t stream) {
  const float* x     = (const float*)d_in[0];
  const float* S     = (const float*)d_in[1];
  const float* wEV1  = (const float*)d_in[2];
  const float* wLSI1 = (const float*)d_in[3];
  const float* b1    = (const float*)d_in[4];
  const float* wEV2  = (const float*)d_in[5];
  const float* wLSI2 = (const float*)d_in[6];
  const float* b2    = (const float*)d_in[7];
  const float* W1    = (const float*)d_in[8];
  const float* bW1   = (const float*)d_in[9];
  const float* W2    = (const float*)d_in[10];
  const float* bW2   = (const float*)d_in[11];
  float* out = (float*)d_out;

  char* w = (char*)d_ws;
  auto alloc = [&](size_t bytes) { char* p = w; w += (bytes + 255) & ~(size_t)255; return p; };
  int*   sp_col = (int*)alloc(512 * 64 * 4);
  int*   sp_cnt = (int*)alloc(512 * 4);
  int*   s_col  = (int*)alloc(512 * 64 * 4);
  float* s_val  = (float*)alloc(512 * 64 * 4);
  int*   s_cnt  = (int*)alloc(512 * 4);
  float* xt     = (float*)alloc((size_t)32768 * 4);
  float* u1     = (float*)alloc((size_t)32768 * 4);
  float* u2     = (float*)alloc((size_t)32768 * 4);
  float* zA1    = (float*)alloc((size_t)8 * 32768 * 4);
  float* zB1    = (float*)alloc((size_t)8 * 32768 * 4);
  float* y1     = (float*)alloc((size_t)8 * 32768 * 4);
  float* zA2    = (float*)alloc((size_t)64 * 32768 * 4);    // 8.4 MB
  float* zB2    = (float*)alloc((size_t)64 * 32768 * 4);
  float* v1     = (float*)alloc((size_t)8 * 32768 * 4);
  float* v2     = (float*)alloc((size_t)8 * 32768 * 4);
  float* y2     = (float*)alloc((size_t)8 * 32768 * 4);
  float* ht     = (float*)alloc((size_t)32768 * 4);
  (void)ws_size; (void)in_sizes; (void)n_in; (void)out_size;

  k_prep<<<128, 256, 0, stream>>>(x, S, sp_col, sp_cnt, s_col, s_val, s_cnt, xt);
  k_l1s0<<<1152, 256, 0, stream>>>(wEV1, sp_col, sp_cnt, s_col, s_val, s_cnt, xt, zA1, u1);
  k_l1s1<<<1152, 256, 0, stream>>>(wEV1, sp_col, sp_cnt, s_col, s_val, s_cnt, zA1, u1, zB1, u2);
  k_l1s2<<<1024, 256, 0, stream>>>(wEV1, sp_col, sp_cnt, zA1, zB1, xt, u1, u2, wLSI1, b1, y1);
  k_l2s0<<<9216, 256, 0, stream>>>(wEV2, sp_col, sp_cnt, s_col, s_val, s_cnt, y1, zA2, v1);
  k_l2s1<<<9216, 256, 0, stream>>>(wEV2, sp_col, sp_cnt, s_col, s_val, s_cnt, zA2, v1, zB2, v2);
  k_l2s2<<<512, 256, 0, stream>>>(wEV2, sp_col, sp_cnt, zA2, zB2, y1, v1, v2, wLSI2, b2, bW1, y2, ht);
  k_gemm1<<<512, 256, 0, stream>>>(W1, y2, bW2, ht, out);
  k_gemm2<<<256, 256, 0, stream>>>(W2, ht, out);
}

// Round 3
// 396.607 us; speedup vs baseline: 1.2686x; 1.2686x over previous
//
#include <hip/hip_runtime.h>
#include <cstdint>
#include <cstddef>

#define NNODE 512
#define MMASK 256
#define ZT 1e-9f
#define NPL 216     // 24 L1 planes + 192 L2 planes

// ---------------- prep: ELL build (pad col=0, w=0) + x transpose ----------------
__global__ __launch_bounds__(256) void k_prep(const float* __restrict__ x,
                                              const float* __restrict__ S,
                                              int* __restrict__ sp_col, int* __restrict__ sp_cnt,
                                              int* __restrict__ s_col, float* __restrict__ s_val,
                                              int* __restrict__ s_cnt,
                                              float* __restrict__ xt) {
  int gtid = blockIdx.x * 256 + threadIdx.x;    // grid 128x256 = 32768
  int W = gtid >> 6, lane = threadIdx.x & 63;
  // transpose x: (B,N) -> (N,B)
  {
    int n = gtid >> 6, b = gtid & 63;
    xt[gtid] = x[b * NNODE + n];
  }
  // ELL fill, one wave per row
  int m = W;
  int csp = 0, cs = 0;
  unsigned long long lt = (1ull << lane) - 1ull;
  for (int ch = 0; ch < 8; ++ch) {
    int n = ch * 64 + lane;
    float s = S[m * NNODE + n];
    bool ps  = (s != 0.f);
    bool psp = ((fabsf(s) + ((m == n) ? 1.f : 0.f)) > ZT) && !((m >= MMASK) && (n >= MMASK));
    unsigned long long msp = __ballot(psp), ms = __ballot(ps);
    if (psp) { int p = csp + __popcll(msp & lt); if (p < 64) sp_col[(m << 6) + p] = n; }
    if (ps)  { int p = cs  + __popcll(ms  & lt); if (p < 64) { s_col[(m << 6) + p] = n; s_val[(m << 6) + p] = s; } }
    csp += __popcll(msp); cs += __popcll(ms);
  }
  if (lane >= csp) sp_col[(m << 6) + lane] = 0;                       // pad col -> 0
  if (lane >= cs)  { s_col[(m << 6) + lane] = 0; s_val[(m << 6) + lane] = 0.f; }
  if (lane == 0) { sp_cnt[m] = (csp < 64 ? csp : 64); s_cnt[m] = (cs < 64 ? cs : 64); }
}

// ---------------- pack one (plane,row): per-lane VECTOR gather from dense row ----
// One global_load_dword per lane (uncoalesced but single-instruction, ~13 distinct
// 64B lines per row) -> coalesced 256B wpk store. No LDS, no scalar-load chain.
__device__ __forceinline__ void pack_one(const float* __restrict__ src,   // dense 512-float row
                                         const int* __restrict__ sp_col,
                                         const int* __restrict__ sp_cnt,
                                         float* __restrict__ wpk,
                                         int pidx, int r, int lane) {
  int cl = sp_col[(r << 6) + lane];
  int cnt = sp_cnt[r];
  float wl = (lane < cnt) ? src[cl] : 0.f;
  wpk[((size_t)pidx << 15) + (r << 6) + lane] = wl;
}

// ---------------- ELL row MAC, scalarized metadata ----------------
// cols/ws are wave-uniform pointers (derived from readfirstlane'd job index):
// the compiler emits batched s_load for them; only the z-gather is a vector load.
// Pads (col 0, w 0) make full-16 chunks safe.
__device__ __forceinline__ float ell_mac_s(const int* __restrict__ cols,
                                           const float* __restrict__ ws,
                                           int cnt,
                                           const float* __restrict__ zin, int lane) {
  float a0 = 0.f, a1 = 0.f, a2 = 0.f, a3 = 0.f;
  for (int base = 0; base < cnt; base += 16) {
#pragma unroll
    for (int i = 0; i < 16; i += 4) {
      int   c0 = cols[base + i    ]; float w0 = ws[base + i    ];
      int   c1 = cols[base + i + 1]; float w1 = ws[base + i + 1];
      int   c2 = cols[base + i + 2]; float w2 = ws[base + i + 2];
      int   c3 = cols[base + i + 3]; float w3 = ws[base + i + 3];
      a0 += w0 * zin[(c0 << 6) + lane];
      a1 += w1 * zin[(c1 << 6) + lane];
      a2 += w2 * zin[(c2 << 6) + lane];
      a3 += w3 * zin[(c3 << 6) + lane];
    }
  }
  return (a0 + a1) + (a2 + a3);
}

// ---------------- pack L1 planes (24x512 jobs) ----------------
__global__ __launch_bounds__(256) void k_packA(const float* __restrict__ wEV1,
                                               const int* __restrict__ sp_col,
                                               const int* __restrict__ sp_cnt,
                                               float* __restrict__ wpk) {
  int lane = threadIdx.x & 63;
  int W = __builtin_amdgcn_readfirstlane((blockIdx.x * 256 + (int)threadIdx.x) >> 6);
  int nwv = (gridDim.x << 2);
  for (int u = W; u < 24 * 512; u += nwv) {
    int p = u >> 9, r = u & 511;
    pack_one(wEV1 + ((size_t)p << 18) + (r << 9), sp_col, sp_cnt, wpk, p, r, lane);
  }
}

// ---------------- layer 1 steps (+ hidden L2-plane packing) ----------------
__global__ __launch_bounds__(256) void k_l1s0(const float* __restrict__ wEV2,
    const float* __restrict__ wpk,
    const int* __restrict__ sp_col, const int* __restrict__ sp_cnt,
    const int* __restrict__ s_col, const float* __restrict__ s_val, const int* __restrict__ s_cnt,
    const float* __restrict__ xt, float* __restrict__ zA1, float* __restrict__ u1,
    float* __restrict__ wpk_out) {
  int lane = threadIdx.x & 63;
  int W = __builtin_amdgcn_readfirstlane((blockIdx.x * 256 + (int)threadIdx.x) >> 6);
  int nwv = (gridDim.x << 2);
  for (int u = W; u < 4608 + 32768; u += nwv) {
    if (u < 4096) {
      int f = u >> 9, r = u & 511;
      zA1[((size_t)f << 15) + (r << 6) + lane] =
          ell_mac_s(sp_col + (r << 6), wpk + ((size_t)(f * 3 + 0) << 15) + (r << 6),
                    sp_cnt[r], xt, lane);
    } else if (u < 4608) {
      int r = u - 4096;
      u1[(r << 6) + lane] =
          ell_mac_s(s_col + (r << 6), s_val + (r << 6), s_cnt[r], xt, lane);
    } else {
      int jj = u - 4608;                          // chunk 0: L2 planes 0..63
      int p2 = jj >> 9, r = jj & 511;
      pack_one(wEV2 + ((size_t)p2 << 18) + (r << 9), sp_col, sp_cnt,
               wpk_out, 24 + p2, r, lane);
    }
  }
}

__global__ __launch_bounds__(256) void k_l1s1(const float* __restrict__ wEV2,
    const float* __restrict__ wpk,
    const int* __restrict__ sp_col, const int* __restrict__ sp_cnt,
    const int* __restrict__ s_col, const float* __restrict__ s_val, const int* __restrict__ s_cnt,
    const float* __restrict__ zA1, const float* __restrict__ u1,
    float* __restrict__ zB1, float* __restrict__ u2,
    float* __restrict__ wpk_out) {
  int lane = threadIdx.x & 63;
  int W = __builtin_amdgcn_readfirstlane((blockIdx.x * 256 + (int)threadIdx.x) >> 6);
  int nwv = (gridDim.x << 2);
  for (int u = W; u < 4608 + 32768; u += nwv) {
    if (u < 4096) {
      int f = u >> 9, r = u & 511;
      zB1[((size_t)f << 15) + (r << 6) + lane] =
          ell_mac_s(sp_col + (r << 6), wpk + ((size_t)(f * 3 + 1) << 15) + (r << 6),
                    sp_cnt[r], zA1 + ((size_t)f << 15), lane);
    } else if (u < 4608) {
      int r = u - 4096;
      u2[(r << 6) + lane] =
          ell_mac_s(s_col + (r << 6), s_val + (r << 6), s_cnt[r], u1, lane);
    } else {
      int jj = u - 4608 + 32768;                  // chunk 1: L2 planes 64..127
      int p2 = jj >> 9, r = jj & 511;
      pack_one(wEV2 + ((size_t)p2 << 18) + (r << 9), sp_col, sp_cnt,
               wpk_out, 24 + p2, r, lane);
    }
  }
}

__global__ __launch_bounds__(256) void k_l1s2(const float* __restrict__ wEV2,
    const float* __restrict__ wpk,
    const int* __restrict__ sp_col, const int* __restrict__ sp_cnt,
    const float* __restrict__ zA1, const float* __restrict__ zB1,
    const float* __restrict__ xt, const float* __restrict__ u1, const float* __restrict__ u2,
    const float* __restrict__ wLSI1, const float* __restrict__ b1, float* __restrict__ y1,
    float* __restrict__ wpk_out) {
  int lane = threadIdx.x & 63;
  int W = __builtin_amdgcn_readfirstlane((blockIdx.x * 256 + (int)threadIdx.x) >> 6);
  int nwv = (gridDim.x << 2);
  for (int u = W; u < 4096 + 32768; u += nwv) {
    if (u < 4096) {
      int f = u >> 9, r = u & 511;
      float a = ell_mac_s(sp_col + (r << 6), wpk + ((size_t)(f * 3 + 2) << 15) + (r << 6),
                          sp_cnt[r], zB1 + ((size_t)f << 15), lane);
      int idx = (r << 6) + lane;
      size_t fi = ((size_t)f << 15) + idx;
      y1[fi] = zA1[fi] + zB1[fi] + a
             + wLSI1[f * 3 + 0] * xt[idx] + wLSI1[f * 3 + 1] * u1[idx]
             + wLSI1[f * 3 + 2] * u2[idx] + b1[f];
    } else {
      int jj = u - 4096 + 65536;                  // chunk 2: L2 planes 128..191
      int p2 = jj >> 9, r = jj & 511;
      pack_one(wEV2 + ((size_t)p2 << 18) + (r << 9), sp_col, sp_cnt,
               wpk_out, 24 + p2, r, lane);
    }
  }
}

// ---------------- layer 2 steps ----------------
__global__ __launch_bounds__(256) void k_l2s0(const float* __restrict__ wpk,
    const int* __restrict__ sp_col, const int* __restrict__ sp_cnt,
    const int* __restrict__ s_col, const float* __restrict__ s_val, const int* __restrict__ s_cnt,
    const float* __restrict__ y1, float* __restrict__ zA2, float* __restrict__ v1) {
  int lane = threadIdx.x & 63;
  int W = __builtin_amdgcn_readfirstlane((blockIdx.x * 256 + (int)threadIdx.x) >> 6);
  int nwv = (gridDim.x << 2);
  for (int u = W; u < 36864; u += nwv) {
    if (u < 32768) {
      int c = u >> 9, r = u & 511;
      int f = c >> 3, g = c & 7;
      zA2[((size_t)c << 15) + (r << 6) + lane] =
          ell_mac_s(sp_col + (r << 6),
                    wpk + ((size_t)(24 + (f * 3 + 0) * 8 + g) << 15) + (r << 6),
                    sp_cnt[r], y1 + ((size_t)g << 15), lane);
    } else {
      int t = u - 32768;
      int g = t >> 9, r = t & 511;
      v1[((size_t)g << 15) + (r << 6) + lane] =
          ell_mac_s(s_col + (r << 6), s_val + (r << 6), s_cnt[r],
                    y1 + ((size_t)g << 15), lane);
    }
  }
}

__global__ __launch_bounds__(256) void k_l2s1(const float* __restrict__ wpk,
    const int* __restrict__ sp_col, const int* __restrict__ sp_cnt,
    const int* __restrict__ s_col, const float* __restrict__ s_val, const int* __restrict__ s_cnt,
    const float* __restrict__ zA2, const float* __restrict__ v1,
    float* __restrict__ zB2, float* __restrict__ v2) {
  int lane = threadIdx.x & 63;
  int W = __builtin_amdgcn_readfirstlane((blockIdx.x * 256 + (int)threadIdx.x) >> 6);
  int nwv = (gridDim.x << 2);
  for (int u = W; u < 36864; u += nwv) {
    if (u < 32768) {
      int c = u >> 9, r = u & 511;
      int f = c >> 3, g = c & 7;
      zB2[((size_t)c << 15) + (r << 6) + lane] =
          ell_mac_s(sp_col + (r << 6),
                    wpk + ((size_t)(24 + (f * 3 + 1) * 8 + g) << 15) + (r << 6),
                    sp_cnt[r], zA2 + ((size_t)c << 15), lane);
    } else {
      int t = u - 32768;
      int g = t >> 9, r = t & 511;
      v2[((size_t)g << 15) + (r << 6) + lane] =
          ell_mac_s(s_col + (r << 6), s_val + (r << 6), s_cnt[r],
                    v1 + ((size_t)g << 15), lane);
    }
  }
}

// k2 step: one (f,r) job covers all 8 g -> direct y2 write, no atomics. ht init folded.
__global__ __launch_bounds__(256) void k_l2s2(const float* __restrict__ wpk,
    const int* __restrict__ sp_col, const int* __restrict__ sp_cnt,
    const float* __restrict__ zA2, const float* __restrict__ zB2,
    const float* __restrict__ y1, const float* __restrict__ v1, const float* __restrict__ v2,
    const float* __restrict__ wLSI2, const float* __restrict__ b2,
    const float* __restrict__ bW1, float* __restrict__ y2, float* __restrict__ ht) {
  int gtid = blockIdx.x * 256 + threadIdx.x;
  int lane = threadIdx.x & 63;
  int W = __builtin_amdgcn_readfirstlane(gtid >> 6);
  int nwv = (gridDim.x << 2);
  if (gtid < 32768) ht[gtid] = bW1[gtid >> 6];
  for (int u = W; u < 4096; u += nwv) {
    int f = u >> 9, r = u & 511;
    int idx = (r << 6) + lane;
    const int* cols = sp_col + (r << 6);
    int cnt = sp_cnt[r];
    float acc = b2[f];
#pragma unroll
    for (int g = 0; g < 8; ++g) {
      int c = f * 8 + g;
      float a = ell_mac_s(cols,
                          wpk + ((size_t)(24 + (f * 3 + 2) * 8 + g) << 15) + (r << 6),
                          cnt, zB2 + ((size_t)c << 15), lane);
      size_t ci = ((size_t)c << 15) + idx;
      size_t gi = ((size_t)g << 15) + idx;
      acc += zA2[ci] + zB2[ci] + a
           + wLSI2[f * 24 + g]      * y1[gi]
           + wLSI2[f * 24 + 8 + g]  * v1[gi]
           + wLSI2[f * 24 + 16 + g] * v2[gi];
    }
    y2[((size_t)f << 15) + idx] = acc;
  }
}

// ---------------- readout ----------------
// 8 K-splits (was 32): 4x fewer atomics per ht address, jobs = 64 pg x 8 ks = 512.
__global__ __launch_bounds__(256) void k_gemm1(const float* __restrict__ W1,
                                               const float* __restrict__ y2,
                                               const float* __restrict__ bW2,
                                               float* __restrict__ ht,
                                               float* __restrict__ out) {
  int gtid = blockIdx.x * 256 + threadIdx.x;
  int lane = threadIdx.x & 63;
  int W = __builtin_amdgcn_readfirstlane(gtid >> 6);
  int nwv = (gridDim.x << 2);
  if (gtid < 8192) out[gtid] = bW2[gtid & 127];
  for (int u = W; u < 512; u += nwv) {
    int pg = u >> 3, ks = u & 7;
    const float* wrow = W1 + (size_t)pg * 8 * 4096 + ks * 512;   // uniform -> s_load
    const float* yb = y2 + ((size_t)(ks * 512) << 6);
    float acc[8] = {0, 0, 0, 0, 0, 0, 0, 0};
    for (int q = 0; q < 512; q += 8) {
      float yv[8];
#pragma unroll
      for (int i = 0; i < 8; ++i) yv[i] = yb[((q + i) << 6) + lane];
#pragma unroll
      for (int i = 0; i < 8; ++i) {
#pragma unroll
        for (int p = 0; p < 8; ++p) acc[p] += wrow[(size_t)p * 4096 + q + i] * yv[i];
      }
    }
#pragma unroll
    for (int p = 0; p < 8; ++p) atomicAdd(&ht[((pg * 8 + p) << 6) + lane], acc[p]);
  }
}

__global__ __launch_bounds__(256) void k_gemm2(const float* __restrict__ W2,
                                               const float* __restrict__ ht,
                                               float* __restrict__ out) {
  int lane = threadIdx.x & 63;
  int W = __builtin_amdgcn_readfirstlane((blockIdx.x * 256 + (int)threadIdx.x) >> 6);
  int nwv = (gridDim.x << 2);
  for (int u = W; u < 1024; u += nwv) {
    int o = u >> 3, qs = u & 7;
    const float* w2 = W2 + (size_t)o * 512 + qs * 64;            // uniform -> s_load
    const float* hb = ht + ((size_t)(qs * 64) << 6);
    float acc = 0.f;
    for (int q = 0; q < 64; q += 8) {
#pragma unroll
      for (int i = 0; i < 8; ++i) acc += w2[q + i] * hb[((q + i) << 6) + lane];
    }
    atomicAdd(&out[lane * 128 + o], acc);
  }
}

extern "C" void kernel_launch(void* const* d_in, const int* in_sizes, int n_in,
                              void* d_out, int out_size, void* d_ws, size_t ws_size,
                              hipStream_t stream) {
  const float* x     = (const float*)d_in[0];
  const float* S     = (const float*)d_in[1];
  const float* wEV1  = (const float*)d_in[2];
  const float* wLSI1 = (const float*)d_in[3];
  const float* b1    = (const float*)d_in[4];
  const float* wEV2  = (const float*)d_in[5];
  const float* wLSI2 = (const float*)d_in[6];
  const float* b2    = (const float*)d_in[7];
  const float* W1    = (const float*)d_in[8];
  const float* bW1   = (const float*)d_in[9];
  const float* W2    = (const float*)d_in[10];
  const float* bW2   = (const float*)d_in[11];
  float* out = (float*)d_out;

  char* w = (char*)d_ws;
  auto alloc = [&](size_t bytes) { char* p = w; w += (bytes + 255) & ~(size_t)255; return p; };
  int*   sp_col = (int*)alloc(512 * 64 * 4);
  int*   sp_cnt = (int*)alloc(512 * 4);
  int*   s_col  = (int*)alloc(512 * 64 * 4);
  float* s_val  = (float*)alloc(512 * 64 * 4);
  int*   s_cnt  = (int*)alloc(512 * 4);
  float* wpk    = (float*)alloc((size_t)NPL * 32768 * 4);   // 28.3 MB
  float* xt     = (float*)alloc((size_t)32768 * 4);
  float* u1     = (float*)alloc((size_t)32768 * 4);
  float* u2     = (float*)alloc((size_t)32768 * 4);
  float* zA1    = (float*)alloc((size_t)8 * 32768 * 4);
  float* zB1    = (float*)alloc((size_t)8 * 32768 * 4);
  float* y1     = (float*)alloc((size_t)8 * 32768 * 4);
  float* zA2    = (float*)alloc((size_t)64 * 32768 * 4);    // 8.4 MB
  float* zB2    = (float*)alloc((size_t)64 * 32768 * 4);
  float* v1     = (float*)alloc((size_t)8 * 32768 * 4);
  float* v2     = (float*)alloc((size_t)8 * 32768 * 4);
  float* y2     = (float*)alloc((size_t)8 * 32768 * 4);
  float* ht     = (float*)alloc((size_t)32768 * 4);
  (void)ws_size; (void)in_sizes; (void)n_in; (void)out_size;

  k_prep<<<128, 256, 0, stream>>>(x, S, sp_col, sp_cnt, s_col, s_val, s_cnt, xt);
  k_packA<<<3072, 256, 0, stream>>>(wEV1, sp_col, sp_cnt, wpk);
  k_l1s0<<<9344, 256, 0, stream>>>(wEV2, wpk, sp_col, sp_cnt, s_col, s_val, s_cnt, xt, zA1, u1, wpk);
  k_l1s1<<<9344, 256, 0, stream>>>(wEV2, wpk, sp_col, sp_cnt, s_col, s_val, s_cnt, zA1, u1, zB1, u2, wpk);
  k_l1s2<<<9216, 256, 0, stream>>>(wEV2, wpk, sp_col, sp_cnt, zA1, zB1, xt, u1, u2, wLSI1, b1, y1, wpk);
  k_l2s0<<<9216, 256, 0, stream>>>(wpk, sp_col, sp_cnt, s_col, s_val, s_cnt, y1, zA2, v1);
  k_l2s1<<<9216, 256, 0, stream>>>(wpk, sp_col, sp_cnt, s_col, s_val, s_cnt, zA2, v1, zB2, v2);
  k_l2s2<<<1024, 256, 0, stream>>>(wpk, sp_col, sp_cnt, zA2, zB2, y1, v1, v2, wLSI2, b2, bW1, y2, ht);
  k_gemm1<<<128, 256, 0, stream>>>(W1, y2, bW2, ht, out);
  k_gemm2<<<256, 256, 0, stream>>>(W2, ht, out);
}